// Round 13
// baseline (786.611 us; speedup 1.0000x reference)
//
#include <hip/hip_runtime.h>
#include <cstdint>
#include <cstddef>

typedef unsigned short u16;
using half4 = __attribute__((ext_vector_type(4))) _Float16;
using half8 = __attribute__((ext_vector_type(8))) _Float16;
using f32x4 = __attribute__((ext_vector_type(4))) float;
using f4    = __attribute__((ext_vector_type(4))) float;
using u32x4 = __attribute__((ext_vector_type(4))) uint32_t;

#define B_    16
#define C_    256
#define H_    128
#define W_    128
#define C4_   64
#define COUT_ 256
#define HW_   (H_ * W_)

#define QK_S  72     // fused Q/K [h][d]: 64 + 8 pad
#define P_S   136    // fused P [h][g]: 128 + 8 pad
#define XP_S  140    // fused epilogue tile [c][h]

#define XT_HALF   ((size_t)B_ * W_ * H_ * C_)                   // 67,108,864 elems/src
#define W16_ELEMS ((size_t)(C4_ * C_ + C4_ * C_ + COUT_ * C_))  // 98,304
#define WS_NEED   ((2 * XT_HALF + W16_ELEMS) * 2)               // 268,632,064 B

__device__ __forceinline__ u16 f16_rn(float f) {
  _Float16 h = (_Float16)f;   // RN
  return __builtin_bit_cast(u16, h);
}

// ---------------------------------------------------------------------------
// Kernel 0: one-time fp32 -> fp16 weight conversion into ws.
// ---------------------------------------------------------------------------
__global__ void __launch_bounds__(256) wconv_kernel(
    const float* __restrict__ Wk, const float* __restrict__ Wq,
    const float* __restrict__ Wv, u16* __restrict__ W16) {
  const int bid = blockIdx.x;
  const int t   = threadIdx.x;
  const float* src;
  u16* dst;
  int idx;
  if (bid < 16)      { src = Wk; dst = W16;                 idx = bid * 1024 + t * 4; }
  else if (bid < 32) { src = Wq; dst = W16 + C4_ * C_;      idx = (bid - 16) * 1024 + t * 4; }
  else               { src = Wv; dst = W16 + 2 * C4_ * C_;  idx = (bid - 32) * 1024 + t * 4; }
  f4 v = *reinterpret_cast<const f4*>(src + idx);
  half4 h;
#pragma unroll
  for (int i = 0; i < 4; ++i) h[i] = (_Float16)v[i];
  *reinterpret_cast<half4*>(dst + idx) = h;
}

// ---------------------------------------------------------------------------
// Kernel 1: xt — streaming transpose-convert (unchanged; ~135 us measured).
// in fp32 [b][c][h][w] -> XT fp16 [src][b][w][h][c].
// ---------------------------------------------------------------------------
__global__ void __launch_bounds__(256) xt_kernel(
    const float* __restrict__ flow, const float* __restrict__ de_out,
    u16* __restrict__ XT) {
  __shared__ uint32_t Lw[128 * 36];   // 18,432 B
  const int t   = threadIdx.x;
  const int bid = blockIdx.x;
  const int cq  = bid & 3;
  const int h   = (bid >> 2) & 127;
  const int b   = (bid >> 9) & 15;
  const int src = bid >> 13;

  const float* in = (src ? de_out : flow) +
                    (size_t)b * C_ * HW_ + (size_t)(cq * 64) * HW_ + (size_t)h * W_;

#pragma unroll
  for (int it = 0; it < 4; ++it) {
    const int c2 = it * 8 + (t >> 5);        // c-pair [0,32)
    const int w4 = (t & 31) * 4;
    const float* r0 = in + (size_t)(2 * c2) * HW_ + w4;
    f4 va = *reinterpret_cast<const f4*>(r0);
    f4 vb = *reinterpret_cast<const f4*>(r0 + HW_);
#pragma unroll
    for (int j = 0; j < 4; ++j) {
      const int w  = w4 + j;
      const int sw = ((w >> 2) & 7) * 4;
      Lw[w * 36 + (c2 ^ sw)] =
          (uint32_t)f16_rn(va[j]) | ((uint32_t)f16_rn(vb[j]) << 16);
    }
  }
  __syncthreads();
  {
    const int w     = t >> 1;
    const int chalf = t & 1;
    const int sw    = ((w >> 2) & 7) * 4;
    u16* dst = XT + (size_t)src * XT_HALF +
               (((size_t)(b * W_ + w)) * H_ + h) * C_ + cq * 64 + chalf * 32;
#pragma unroll
    for (int k = 0; k < 4; ++k) {
      const int c2b = (chalf * 16 + k * 4) ^ sw;
      u32x4 v = *reinterpret_cast<const u32x4*>(&Lw[w * 36 + c2b]);
      *reinterpret_cast<u32x4*>(dst + k * 8) = v;
    }
  }
}

// ---------------------------------------------------------------------------
// Kernel 2: fused QKV-projection + column attention. Block = (b,w), 8 waves.
// R12 fused was 1 block/CU (VT in LDS = 102.9 KB) -> ~57 us/block serial.
// fused2: V goes to GLOBAL, overlaying each wave's OWN 16 rows of the xf
// column it just consumed (register data-deps order reads before stores;
// cross-wave visibility via __syncthreads' vmcnt drain; PV reads V with the
// R4-proven global-V fragment path, L2-hot). LDS 36.9 KB, VGPR capped via
// two-pass accv + __launch_bounds__(512,4) -> 2 blocks/CU = 16 waves.
// ---------------------------------------------------------------------------
__device__ __forceinline__ const half8* whfrag(const u16* __restrict__ Wm16,
                                               int row, int ks, int lg) {
  return reinterpret_cast<const half8*>(Wm16 + (size_t)row * C_ + ks * 32 + lg * 8);
}

__global__ void __launch_bounds__(512, 4) fused_kernel(
    u16* XTbuf,  // NOT restrict: V overlays xf, out overlays xd
    const u16* __restrict__ W16,
    const float* __restrict__ bq, const float* __restrict__ bk,
    const float* __restrict__ bv) {
  __shared__ __align__(16) u16 lds[2 * 128 * QK_S];   // 36,864 B (P/epi overlay)
  u16* ldsQ = lds;                        // [128][72]
  u16* ldsK = lds + 128 * QK_S;           // [128][72]

  const int t   = threadIdx.x;
  const int bid = blockIdx.x;
  const int sw  = (bid & 7) * 256 + (bid >> 3);  // bijective (2048 % 8 == 0)
  const int b   = sw >> 7;
  const int w   = sw & 127;
  const int lane = t & 63;
  const int wv   = t >> 6;        // 0..7 : wave owns h-rows [wv*16, wv*16+16)
  const int col  = lane & 15;
  const int lg   = lane >> 4;

  u16* xf = XTbuf + ((size_t)(b * W_) + w) * (H_ * C_);            // flow col / V
  u16* xd = XTbuf + XT_HALF + ((size_t)(b * W_) + w) * (H_ * C_);  // de col / out

  const u16* Wk16 = W16;
  const u16* Wq16 = W16 + C4_ * C_;
  const u16* Wv16 = W16 + 2 * C4_ * C_;

  f32x4 zero = {0.f, 0.f, 0.f, 0.f};

  // ---- load A-fragments for wave's 16 flow pixels ----
  half8 af[8];
#pragma unroll
  for (int ks = 0; ks < 8; ++ks)
    af[ks] = *reinterpret_cast<const half8*>(
        xf + (size_t)(wv * 16 + col) * C_ + ks * 32 + lg * 8);

  // ---- K projection -> ldsK ----
  {
    f32x4 acck[4];
#pragma unroll
    for (int i = 0; i < 4; ++i) acck[i] = zero;
#pragma unroll
    for (int ks = 0; ks < 8; ++ks)
#pragma unroll
      for (int nt = 0; nt < 4; ++nt)
        acck[nt] = __builtin_amdgcn_mfma_f32_16x16x32_f16(
            af[ks], *whfrag(Wk16, nt * 16 + col, ks, lg), acck[nt], 0, 0, 0);
#pragma unroll
    for (int nt = 0; nt < 4; ++nt) {
      const float bias = bk[nt * 16 + col];
#pragma unroll
      for (int r = 0; r < 4; ++r)
        ldsK[(wv * 16 + lg * 4 + r) * QK_S + nt * 16 + col] =
            f16_rn(acck[nt][r] + bias);
    }
  }

  // ---- V projection: two passes of 8 nt; store overlays wave's OWN xf rows.
  // V[g][c] at xf[(g>>3)*2048 + c*8 + (g&7)]; wave's g = wv*16+lg*4+r ->
  // goct = wv*2+(lg>>1) in [wv*2, wv*2+2): rows 16wv..16wv+15 = its af rows.
  {
    const int goct = wv * 2 + (lg >> 1);
    const int hl0  = (lg & 1) * 4;
#pragma unroll
    for (int pass = 0; pass < 2; ++pass) {
      f32x4 accv[8];
#pragma unroll
      for (int i = 0; i < 8; ++i) accv[i] = zero;
#pragma unroll
      for (int ks = 0; ks < 8; ++ks)
#pragma unroll
        for (int j = 0; j < 8; ++j)
          accv[j] = __builtin_amdgcn_mfma_f32_16x16x32_f16(
              af[ks], *whfrag(Wv16, (pass * 8 + j) * 16 + col, ks, lg),
              accv[j], 0, 0, 0);
#pragma unroll
      for (int j = 0; j < 8; ++j) {
        const int c = (pass * 8 + j) * 16 + col;
        const float bias = bv[c];
        half4 pk;
#pragma unroll
        for (int r = 0; r < 4; ++r) pk[r] = (_Float16)(accv[j][r] + bias);
        *reinterpret_cast<half4*>(xf + (size_t)goct * 2048 + c * 8 + hl0) = pk;
      }
    }
  }

  // ---- Q projection -> ldsQ ----
  {
#pragma unroll
    for (int ks = 0; ks < 8; ++ks)
      af[ks] = *reinterpret_cast<const half8*>(
          xd + (size_t)(wv * 16 + col) * C_ + ks * 32 + lg * 8);
    f32x4 accq[4];
#pragma unroll
    for (int i = 0; i < 4; ++i) accq[i] = zero;
#pragma unroll
    for (int ks = 0; ks < 8; ++ks)
#pragma unroll
      for (int nt = 0; nt < 4; ++nt)
        accq[nt] = __builtin_amdgcn_mfma_f32_16x16x32_f16(
            af[ks], *whfrag(Wq16, nt * 16 + col, ks, lg), accq[nt], 0, 0, 0);
#pragma unroll
    for (int nt = 0; nt < 4; ++nt) {
      const float bias = bq[nt * 16 + col];
#pragma unroll
      for (int r = 0; r < 4; ++r)
        ldsQ[(wv * 16 + lg * 4 + r) * QK_S + nt * 16 + col] =
            f16_rn(accq[nt][r] + bias);
    }
  }
  __syncthreads();   // Q,K in LDS; V stores drained (vmcnt(0)) -> visible

  // ---- E = Q K^T : wave's 16 q-rows x 128 g ----
  f32x4 e[8];
#pragma unroll
  for (int gt = 0; gt < 8; ++gt) e[gt] = zero;
#pragma unroll
  for (int ks = 0; ks < 2; ++ks) {
    const half8 aq = *reinterpret_cast<const half8*>(
        &ldsQ[(wv * 16 + col) * QK_S + ks * 32 + lg * 8]);
#pragma unroll
    for (int gt = 0; gt < 8; ++gt) {
      const half8 bkf = *reinterpret_cast<const half8*>(
          &ldsK[(gt * 16 + col) * QK_S + ks * 32 + lg * 8]);
      e[gt] = __builtin_amdgcn_mfma_f32_16x16x32_f16(aq, bkf, e[gt], 0, 0, 0);
    }
  }
  __syncthreads();   // Q/K dead -> region becomes P

  u16* ldsP = lds;   // [128][P_S] = 34,816 B
#pragma unroll
  for (int r = 0; r < 4; ++r) {
    float m = -1e30f;
#pragma unroll
    for (int gt = 0; gt < 8; ++gt) m = fmaxf(m, e[gt][r]);
#pragma unroll
    for (int off = 1; off < 16; off <<= 1) m = fmaxf(m, __shfl_xor(m, off));
    float s = 0.f;
#pragma unroll
    for (int gt = 0; gt < 8; ++gt) {
      float p = __expf(e[gt][r] - m);
      e[gt][r] = p;
      s += p;
    }
#pragma unroll
    for (int off = 1; off < 16; off <<= 1) s += __shfl_xor(s, off);
    const float inv = 1.f / s;
    const int hh = wv * 16 + lg * 4 + r;
#pragma unroll
    for (int gt = 0; gt < 8; ++gt)
      ldsP[hh * P_S + gt * 16 + col] = f16_rn(e[gt][r] * inv);
  }
  // P rows are wave-private: in-wave ds ordering suffices before PV.

  // ---- O = P V : A from ldsP, B = V fragments from global (L2-hot) ----
  f32x4 o[16];
#pragma unroll
  for (int ct = 0; ct < 16; ++ct) o[ct] = zero;
#pragma unroll
  for (int ks = 0; ks < 4; ++ks) {
    const half8 ap = *reinterpret_cast<const half8*>(
        &ldsP[(wv * 16 + col) * P_S + ks * 32 + lg * 8]);
#pragma unroll
    for (int ct = 0; ct < 16; ++ct) {
      const half8 bvf = *reinterpret_cast<const half8*>(
          xf + (size_t)(ks * 4 + lg) * 2048 + (ct * 16 + col) * 8);
      o[ct] = __builtin_amdgcn_mfma_f32_16x16x32_f16(ap, bvf, o[ct], 0, 0, 0);
    }
  }

  // ---- epilogue: LDS-transpose 64c x 128h tiles -> fp16 out col [c][h] ----
  u16* ldsX = lds;
#pragma unroll
  for (int ctg = 0; ctg < 4; ++ctg) {
    __syncthreads();   // P dead (first iter) / previous tile consumed
#pragma unroll
    for (int j = 0; j < 4; ++j) {
      const int ct    = ctg * 4 + j;
      const int c_loc = j * 16 + col;
      half4 pk;
#pragma unroll
      for (int r = 0; r < 4; ++r) pk[r] = (_Float16)o[ct][r];
      *reinterpret_cast<half4*>(&ldsX[c_loc * XP_S + wv * 16 + lg * 4]) = pk;
    }
    __syncthreads();
    const int c_loc = t >> 3;          // [0,64)
    const int h0    = (t & 7) * 16;
    u16* dp = xd + (ctg * 64 + c_loc) * 128 + h0;
    *reinterpret_cast<half8*>(dp) =
        *reinterpret_cast<const half8*>(&ldsX[c_loc * XP_S + h0]);
    *reinterpret_cast<half8*>(dp + 8) =
        *reinterpret_cast<const half8*>(&ldsX[c_loc * XP_S + h0 + 8]);
  }
}

// ---------------------------------------------------------------------------
// Kernel 3: out_tmp[b][w][f] fp16 -> out[b][f][w] fp32   (f = c*128 + h)
// ---------------------------------------------------------------------------
__global__ void __launch_bounds__(256) transpose_kernel(
    const u16* __restrict__ T, float* __restrict__ out) {
  __shared__ float lds[64 * 132];
  const int t   = threadIdx.x;
  const int bid = blockIdx.x;
  const int b   = bid >> 9;
  const int ft  = bid & 511;  // f-tile of 64

  {
    const int w  = t >> 1;
    const int fo = (t & 1) * 32;
    const u16* src = T + ((size_t)(b * W_ + w) << 15) + ft * 64 + fo;
#pragma unroll
    for (int k = 0; k < 4; ++k) {
      half8 v = *reinterpret_cast<const half8*>(src + k * 8);
#pragma unroll
      for (int e = 0; e < 8; ++e)
        lds[(fo + k * 8 + e) * 132 + w] = (float)v[e];
    }
  }
  __syncthreads();
  {
    const int f_loc = t >> 2;
    const int w0    = (t & 3) * 32;
    float* dst = out + (size_t)b * (COUT_ * HW_) + (size_t)(ft * 64 + f_loc) * 128 + w0;
#pragma unroll
    for (int k = 0; k < 8; ++k) {
      f4 v4;
#pragma unroll
      for (int e = 0; e < 4; ++e) v4[e] = lds[f_loc * 132 + w0 + k * 4 + e];
      *reinterpret_cast<f4*>(dst + k * 4) = v4;
    }
  }
}

extern "C" void kernel_launch(void* const* d_in, const int* in_sizes, int n_in,
                              void* d_out, int out_size, void* d_ws, size_t ws_size,
                              hipStream_t stream) {
  const float* flow   = (const float*)d_in[0];
  const float* de_out = (const float*)d_in[1];
  const float* Wq = (const float*)d_in[2];
  const float* bq = (const float*)d_in[3];
  const float* Wk = (const float*)d_in[4];
  const float* bk = (const float*)d_in[5];
  const float* Wv = (const float*)d_in[6];
  const float* bv = (const float*)d_in[7];
  float* out = (float*)d_out;

  u16* XTws = (u16*)d_ws;                 // [src][b][w][h][c] fp16; flow half
                                          // becomes V, de half becomes out_tmp
  u16* W16  = XTws + 2 * XT_HALF;         // [Wk16|Wq16|Wv16] fp16
  // total ws use: 268,632,064 B

  wconv_kernel<<<96, 256, 0, stream>>>(Wk, Wq, Wv, W16);
  xt_kernel<<<2 * B_ * H_ * 4, 256, 0, stream>>>(flow, de_out, XTws);
  fused_kernel<<<B_ * W_, 512, 0, stream>>>(XTws, W16, bq, bk, bv);
  transpose_kernel<<<B_ * 512, 256, 0, stream>>>(XTws + XT_HALF, out);
}

// Round 14
// 445.721 us; speedup vs baseline: 1.7648x; 1.7648x over previous
//
#include <hip/hip_runtime.h>
#include <cstdint>
#include <cstddef>

typedef unsigned short u16;
using half4 = __attribute__((ext_vector_type(4))) _Float16;
using half8 = __attribute__((ext_vector_type(8))) _Float16;
using f32x4 = __attribute__((ext_vector_type(4))) float;
using f4    = __attribute__((ext_vector_type(4))) float;

#define B_    16
#define C_    256
#define H_    128
#define W_    128
#define C4_   64
#define COUT_ 256
#define HW_   (H_ * W_)

#define T_S       72    // qkv T [w][c-quarter]: 64 + 8 pad (octet-swizzled)
#define QK_S      72    // attn Q/K [h][d]: 64 + 8 pad
#define P_S       136   // attn P [h][g]: 128 + 8 pad
#define XP_S      140   // attn epilogue tile [c][h]
#define O_S       72    // qkv out tile [w][d]: 64 + 8 pad

#define Q_ELEMS   ((size_t)B_ * W_ * H_ * C4_)      // 16,777,216
#define V_ELEMS   ((size_t)B_ * W_ * H_ * COUT_)    // 67,108,864
#define W16_ELEMS ((size_t)(C4_ * C_ + C4_ * C_ + COUT_ * C_))  // 98,304
#define WS_NEED   ((2 * Q_ELEMS + 2 * V_ELEMS + W16_ELEMS) * 2)

__device__ __forceinline__ u16 f16_rn(float f) {
  _Float16 h = (_Float16)f;   // RN
  return __builtin_bit_cast(u16, h);
}

__device__ __forceinline__ void gload16(const void* g, void* l) {
  __builtin_amdgcn_global_load_lds(
      (const __attribute__((address_space(1))) void*)g,
      (__attribute__((address_space(3))) void*)l, 16, 0, 0);
}

// ---------------------------------------------------------------------------
// Kernel 0: one-time fp32 -> fp16 weight conversion into ws.
// ---------------------------------------------------------------------------
__global__ void __launch_bounds__(256) wconv_kernel(
    const float* __restrict__ Wk, const float* __restrict__ Wq,
    const float* __restrict__ Wv, u16* __restrict__ W16) {
  const int bid = blockIdx.x;
  const int t   = threadIdx.x;
  const float* src;
  u16* dst;
  int idx;
  if (bid < 16)      { src = Wk; dst = W16;                 idx = bid * 1024 + t * 4; }
  else if (bid < 32) { src = Wq; dst = W16 + C4_ * C_;      idx = (bid - 16) * 1024 + t * 4; }
  else               { src = Wv; dst = W16 + 2 * C4_ * C_;  idx = (bid - 32) * 1024 + t * 4; }
  f4 v = *reinterpret_cast<const f4*>(src + idx);
  half4 h;
#pragma unroll
  for (int i = 0; i < 4; ++i) h[i] = (_Float16)v[i];
  *reinterpret_cast<half4*>(dst + idx) = h;
}

// ---------------------------------------------------------------------------
// Kernel 1: Q/K/V projections — R9 restore (best measured: 272 us, clean
// FETCH/WRITE). Counted-vmcnt pipelined staging; w-contiguous reads; K/Q via
// LDS O-tile full-coverage stores; V sibling-merged scatter.
// ---------------------------------------------------------------------------
__device__ __forceinline__ const half8* afragq(const u16* __restrict__ T,
                                               int w16, int ksl, int lg) {
  int oct = (ksl * 4 + lg) ^ ((w16 >> 2) & 7);
  return reinterpret_cast<const half8*>(&T[w16 * T_S + oct * 8]);
}

__device__ __forceinline__ const half8* whfrag(const u16* __restrict__ Wm16,
                                               int row, int ks, int lg) {
  return reinterpret_cast<const half8*>(Wm16 + (size_t)row * C_ + ks * 32 + lg * 8);
}

__global__ void __launch_bounds__(256, 3) qkv_kernel(
    const float* __restrict__ flow, const float* __restrict__ de_out,
    const u16* __restrict__ W16,
    const float* __restrict__ bq, const float* __restrict__ bk,
    const float* __restrict__ bv,
    u16* __restrict__ Qws, u16* __restrict__ Kws, u16* __restrict__ Vws) {
  __shared__ __align__(16) unsigned char ldsraw[2 * 16384 + 64 * T_S * 2];
  float* Fbuf[2] = {reinterpret_cast<float*>(ldsraw),
                    reinterpret_cast<float*>(ldsraw + 16384)};
  u16* T = reinterpret_cast<u16*>(ldsraw + 32768);        // [64][72] fp16 quarter
  u16* O = reinterpret_cast<u16*>(ldsraw);                // [64][72] out tile

  const int t    = threadIdx.x;
  const int bid  = blockIdx.x;
  // sibling-colocating decomposition (keeps V-write L2 merging)
  const int g      = (bid & 7) | ((bid >> 6) << 3);  // [0,1024)
  const int hlow   = (bid >> 3) & 7;
  const int w0     = (g & 1) * 64;
  const int hgrp   = (g >> 1) & 15;
  const int b      = (g >> 5) & 15;
  const int srcsel = g >> 9;
  const int h      = hgrp * 8 + hlow;
  const int lane = t & 63;
  const int wv   = t >> 6;
  const int col  = lane & 15;
  const int lg   = lane >> 4;

  const u16* Wk16 = W16;
  const u16* Wq16 = W16 + C4_ * C_;
  const u16* Wv16 = W16 + 2 * C4_ * C_;

  const float* src =
      (srcsel ? de_out : flow) + (size_t)b * C_ * HW_ + (size_t)h * W_ + w0;

  f32x4 zero = {0.f, 0.f, 0.f, 0.f};
  f32x4 acc0[4];                 // K (srcsel=0) or Q (srcsel=1)
  f32x4 accV[4][4];              // V (srcsel=0 only)
#pragma unroll
  for (int i = 0; i < 4; ++i) acc0[i] = zero;
#pragma unroll
  for (int j = 0; j < 4; ++j)
#pragma unroll
    for (int i = 0; i < 4; ++i) accV[j][i] = zero;

  // ---- prologue: issue quarter 0 ----
#pragma unroll
  for (int i = 0; i < 4; ++i) {
    const int rr0 = wv * 16 + i * 4;
    gload16(src + (size_t)(rr0 + (lane >> 4)) * HW_ + (lane & 15) * 4,
            Fbuf[0] + rr0 * 64);
  }

#pragma unroll
  for (int q = 0; q < 4; ++q) {
    float* Fc = Fbuf[q & 1];
    float* Fn = Fbuf[(q + 1) & 1];
    if (q < 3) {
      const float* s = src + (size_t)((q + 1) * 64) * HW_;
#pragma unroll
      for (int i = 0; i < 4; ++i) {
        const int rr0 = wv * 16 + i * 4;
        gload16(s + (size_t)(rr0 + (lane >> 4)) * HW_ + (lane & 15) * 4,
                Fn + rr0 * 64);
      }
      asm volatile("s_waitcnt vmcnt(4) lgkmcnt(0)\ns_barrier" ::: "memory");
    } else {
      asm volatile("s_waitcnt vmcnt(0) lgkmcnt(0)\ns_barrier" ::: "memory");
    }
    __builtin_amdgcn_sched_barrier(0);

    // ---- convert quarter: Fc[rr][w] fp32 -> T[w][c_loc] fp16 (octet swizzle)
#pragma unroll
    for (int i = 0; i < 2; ++i) {
      const int flat = i * 256 + t;            // [0,512)
      const int wq = flat & 15;                // w-quad
      const int pp = flat >> 4;                // local c-pair [0,32)
      const f4 fa = *reinterpret_cast<const f4*>(&Fc[(2 * pp) * 64 + wq * 4]);
      const f4 fb = *reinterpret_cast<const f4*>(&Fc[(2 * pp + 1) * 64 + wq * 4]);
      const int c_loc = 2 * pp;                // [0,64)
      const int oct   = (c_loc >> 3) ^ (wq & 7);
#pragma unroll
      for (int j = 0; j < 4; ++j) {
        const int w = wq * 4 + j;
        uint32_t pk = (uint32_t)f16_rn(fa[j]) | ((uint32_t)f16_rn(fb[j]) << 16);
        *reinterpret_cast<uint32_t*>(&T[w * T_S + oct * 8 + (c_loc & 7)]) = pk;
      }
    }
    asm volatile("s_waitcnt lgkmcnt(0)\ns_barrier" ::: "memory");
    __builtin_amdgcn_sched_barrier(0);

    // ---- MFMA this quarter's two k-chunks ----
#pragma unroll
    for (int ksl = 0; ksl < 2; ++ksl) {
      const int ks = 2 * q + ksl;
      if (srcsel == 0) {
        const half8 bK = *whfrag(Wk16, wv * 16 + col, ks, lg);
        half8 bV[4];
#pragma unroll
        for (int j = 0; j < 4; ++j)
          bV[j] = *whfrag(Wv16, (wv * 4 + j) * 16 + col, ks, lg);
#pragma unroll
        for (int wt = 0; wt < 4; ++wt) {
          const half8 afr = *afragq(T, wt * 16 + col, ksl, lg);
          acc0[wt] = __builtin_amdgcn_mfma_f32_16x16x32_f16(afr, bK, acc0[wt], 0, 0, 0);
#pragma unroll
          for (int j = 0; j < 4; ++j)
            accV[j][wt] =
                __builtin_amdgcn_mfma_f32_16x16x32_f16(afr, bV[j], accV[j][wt], 0, 0, 0);
        }
      } else {
        const half8 bQ = *whfrag(Wq16, wv * 16 + col, ks, lg);
#pragma unroll
        for (int wt = 0; wt < 4; ++wt) {
          const half8 afr = *afragq(T, wt * 16 + col, ksl, lg);
          acc0[wt] = __builtin_amdgcn_mfma_f32_16x16x32_f16(afr, bQ, acc0[wt], 0, 0, 0);
        }
      }
    }
  }

  // ---- epilogue ----
  if (srcsel == 0) {
    {  // K via LDS O-tile (reuses F0)
      const float bias = bk[wv * 16 + col];
      __syncthreads();
#pragma unroll
      for (int wt = 0; wt < 4; ++wt)
#pragma unroll
        for (int r = 0; r < 4; ++r)
          O[(wt * 16 + lg * 4 + r) * O_S + wv * 16 + col] = f16_rn(acc0[wt][r] + bias);
      __syncthreads();
#pragma unroll
      for (int i = 0; i < 2; ++i) {
        const int item = i * 256 + t;      // [0,512)
        const int wl = item >> 3;          // [0,64)
        const int d0 = (item & 7) * 8;     // 0..56
        *reinterpret_cast<half8*>(
            &Kws[(((size_t)b * W_ + w0 + wl) * H_ + h) * C4_ + d0]) =
            *reinterpret_cast<const half8*>(&O[wl * O_S + d0]);
      }
    }
    // V: sibling-merged scatter, layout [b][w][g>>3][c][g&7]
#pragma unroll
    for (int j = 0; j < 4; ++j) {
      const int co = (wv * 4 + j) * 16 + col;
      const float bias = bv[co];
#pragma unroll
      for (int wt = 0; wt < 4; ++wt)
#pragma unroll
        for (int r = 0; r < 4; ++r) {
          int w = w0 + wt * 16 + lg * 4 + r;
          Vws[(size_t)(b * W_ + w) * 32768 + ((h >> 3) * COUT_ + co) * 8 + (h & 7)] =
              f16_rn(accV[j][wt][r] + bias);
        }
    }
  } else {
    const float bias = bq[wv * 16 + col];
    __syncthreads();
#pragma unroll
    for (int wt = 0; wt < 4; ++wt)
#pragma unroll
      for (int r = 0; r < 4; ++r)
        O[(wt * 16 + lg * 4 + r) * O_S + wv * 16 + col] = f16_rn(acc0[wt][r] + bias);
    __syncthreads();
#pragma unroll
    for (int i = 0; i < 2; ++i) {
      const int item = i * 256 + t;
      const int wl = item >> 3;
      const int d0 = (item & 7) * 8;
      *reinterpret_cast<half8*>(
          &Qws[(((size_t)b * W_ + w0 + wl) * H_ + h) * C4_ + d0]) =
          *reinterpret_cast<const half8*>(&O[wl * O_S + d0]);
    }
  }
}

// ---------------------------------------------------------------------------
// Kernel 2: per-(b,w)-column attention — now 512 threads / 8 WAVES.
// R9 attn was 4 waves, VGPR 100, ~8 waves/CU -> per-CU memory rate ~9 GB/s
// (the occupancy-rate curve from R11/R12). 8-wave version: each wave owns 16
// q-rows, o[16] = 64 VGPR (halved), __launch_bounds__(512,4) caps VGPR at 128
// -> 2 blocks x 8 waves = 16 waves/CU, 2x R9. Numerics identical (this is
// R12's verified attention section reading Q/K/V from ws).
// ---------------------------------------------------------------------------
template <int EPI>
__global__ void __launch_bounds__(512, 4) attn_kernel(
    const u16* __restrict__ Qws, const u16* __restrict__ Kws,
    const u16* __restrict__ Vws, u16* __restrict__ out_tmp,
    float* __restrict__ out) {
  __shared__ __align__(16) u16 ldsQK[2 * 128 * QK_S];  // P and epi-tile overlay

  const int t   = threadIdx.x;
  const int bid = blockIdx.x;
  const int sw  = (bid & 7) * 256 + (bid >> 3);  // bijective (2048 % 8 == 0)
  const int b   = sw >> 7;
  const int w   = sw & 127;
  const int lane = t & 63;
  const int wv   = t >> 6;        // 0..7 : wave owns h-rows [wv*16, wv*16+16)
  const int col  = lane & 15;
  const int lg   = lane >> 4;

  const u16* qc    = Qws + ((size_t)b * W_ + w) * H_ * C4_;
  const u16* kc    = Kws + ((size_t)b * W_ + w) * H_ * C4_;
  const u16* vbase = Vws + (size_t)(b * W_ + w) * 32768;

  u16* ldsQ = ldsQK;
  u16* ldsK = ldsQK + 128 * QK_S;

  // ---- stage Q, K: 1024 half8 items each, 512 threads -> 2 iters ----
#pragma unroll
  for (int i = 0; i < 2; ++i) {
    int item = i * 512 + t;
    int hh   = item >> 3;
    int d0   = (item & 7) * 8;
    *reinterpret_cast<half8*>(&ldsQ[hh * QK_S + d0]) =
        *reinterpret_cast<const half8*>(qc + item * 8);
    *reinterpret_cast<half8*>(&ldsK[hh * QK_S + d0]) =
        *reinterpret_cast<const half8*>(kc + item * 8);
  }
  __syncthreads();

  f32x4 zero = {0.f, 0.f, 0.f, 0.f};

  // ---- E = Q K^T : wave's 16 q-rows x 128 g ----
  f32x4 e[8];
#pragma unroll
  for (int gt = 0; gt < 8; ++gt) e[gt] = zero;
#pragma unroll
  for (int ks = 0; ks < 2; ++ks) {
    const half8 aq = *reinterpret_cast<const half8*>(
        &ldsQ[(wv * 16 + col) * QK_S + ks * 32 + lg * 8]);
#pragma unroll
    for (int gt = 0; gt < 8; ++gt) {
      const half8 bkf = *reinterpret_cast<const half8*>(
          &ldsK[(gt * 16 + col) * QK_S + ks * 32 + lg * 8]);
      e[gt] = __builtin_amdgcn_mfma_f32_16x16x32_f16(aq, bkf, e[gt], 0, 0, 0);
    }
  }
  __syncthreads();   // Q/K dead -> region becomes P

  u16* ldsP = ldsQK;   // [128][P_S] = 34,816 B

  // ---- softmax over g; wave-private rows ----
#pragma unroll
  for (int r = 0; r < 4; ++r) {
    float m = -1e30f;
#pragma unroll
    for (int gt = 0; gt < 8; ++gt) m = fmaxf(m, e[gt][r]);
#pragma unroll
    for (int off = 1; off < 16; off <<= 1) m = fmaxf(m, __shfl_xor(m, off));
    float s = 0.f;
#pragma unroll
    for (int gt = 0; gt < 8; ++gt) {
      float p = __expf(e[gt][r] - m);
      e[gt][r] = p;
      s += p;
    }
#pragma unroll
    for (int off = 1; off < 16; off <<= 1) s += __shfl_xor(s, off);
    const float inv = 1.f / s;
    const int hh = wv * 16 + lg * 4 + r;
#pragma unroll
    for (int gt = 0; gt < 8; ++gt)
      ldsP[hh * P_S + gt * 16 + col] = f16_rn(e[gt][r] * inv);
  }
  // P rows are wave-private: in-wave ds ordering suffices before PV.

  // ---- O = P V : wave's 16 h-rows x 256 c; V fragments from global ----
  f32x4 o[16];
#pragma unroll
  for (int ct = 0; ct < 16; ++ct) o[ct] = zero;
#pragma unroll
  for (int ks = 0; ks < 4; ++ks) {
    const half8 ap = *reinterpret_cast<const half8*>(
        &ldsP[(wv * 16 + col) * P_S + ks * 32 + lg * 8]);
#pragma unroll
    for (int ct = 0; ct < 16; ++ct) {
      const half8 bvf = *reinterpret_cast<const half8*>(
          vbase + ((ks * 4 + lg) * COUT_ + ct * 16 + col) * 8);
      o[ct] = __builtin_amdgcn_mfma_f32_16x16x32_f16(ap, bvf, o[ct], 0, 0, 0);
    }
  }

  if (EPI == 1) {
    // ---- epilogue: LDS-transpose 64c x 128h tiles -> fp16 out_tmp[b][w][c][h]
    u16* ldsX = ldsQK;
    u16* dst_col = out_tmp + ((size_t)(b * W_ + w) << 15);
#pragma unroll
    for (int ctg = 0; ctg < 4; ++ctg) {
      __syncthreads();   // P dead (first iter) / previous tile consumed
#pragma unroll
      for (int j = 0; j < 4; ++j) {
        const int ct    = ctg * 4 + j;
        const int c_loc = j * 16 + col;
        half4 pk;
#pragma unroll
        for (int r = 0; r < 4; ++r) pk[r] = (_Float16)o[ct][r];
        *reinterpret_cast<half4*>(&ldsX[c_loc * XP_S + wv * 16 + lg * 4]) = pk;
      }
      __syncthreads();
      const int c_loc = t >> 3;          // [0,64)
      const int h0    = (t & 7) * 16;
      u16* dp = dst_col + (ctg * 64 + c_loc) * 128 + h0;
      *reinterpret_cast<half8*>(dp) =
          *reinterpret_cast<const half8*>(&ldsX[c_loc * XP_S + h0]);
      *reinterpret_cast<half8*>(dp + 8) =
          *reinterpret_cast<const half8*>(&ldsX[c_loc * XP_S + h0 + 8]);
    }
  } else {
    // ---- fallback: direct fp32 scatter ----
    float* outp = out + (size_t)b * COUT_ * HW_ + w;
#pragma unroll
    for (int ct = 0; ct < 16; ++ct)
#pragma unroll
      for (int r = 0; r < 4; ++r) {
        int hrow = wv * 16 + lg * 4 + r;
        int c = ct * 16 + col;
        outp[((size_t)c * H_ + hrow) * W_] = o[ct][r];
      }
  }
}

// ---------------------------------------------------------------------------
// Kernel 3: out_tmp[b][w][f] fp16 -> out[b][f][w] fp32   (f = c*128 + h)
// ---------------------------------------------------------------------------
__global__ void __launch_bounds__(256) transpose_kernel(
    const u16* __restrict__ T, float* __restrict__ out) {
  __shared__ float lds[64 * 132];
  const int t   = threadIdx.x;
  const int bid = blockIdx.x;
  const int b   = bid >> 9;
  const int ft  = bid & 511;  // f-tile of 64

  {
    const int w  = t >> 1;
    const int fo = (t & 1) * 32;
    const u16* src = T + ((size_t)(b * W_ + w) << 15) + ft * 64 + fo;
#pragma unroll
    for (int k = 0; k < 4; ++k) {
      half8 v = *reinterpret_cast<const half8*>(src + k * 8);
#pragma unroll
      for (int e = 0; e < 8; ++e)
        lds[(fo + k * 8 + e) * 132 + w] = (float)v[e];
    }
  }
  __syncthreads();
  {
    const int f_loc = t >> 2;
    const int w0    = (t & 3) * 32;
    float* dst = out + (size_t)b * (COUT_ * HW_) + (size_t)(ft * 64 + f_loc) * 128 + w0;
#pragma unroll
    for (int k = 0; k < 8; ++k) {
      f4 v4;
#pragma unroll
      for (int e = 0; e < 4; ++e) v4[e] = lds[f_loc * 132 + w0 + k * 4 + e];
      *reinterpret_cast<f4*>(dst + k * 4) = v4;
    }
  }
}

extern "C" void kernel_launch(void* const* d_in, const int* in_sizes, int n_in,
                              void* d_out, int out_size, void* d_ws, size_t ws_size,
                              hipStream_t stream) {
  const float* flow   = (const float*)d_in[0];
  const float* de_out = (const float*)d_in[1];
  const float* Wq = (const float*)d_in[2];
  const float* bq = (const float*)d_in[3];
  const float* Wk = (const float*)d_in[4];
  const float* bk = (const float*)d_in[5];
  const float* Wv = (const float*)d_in[6];
  const float* bv = (const float*)d_in[7];
  float* out = (float*)d_out;

  u16* Qws = (u16*)d_ws;                 // [b][w][h][d]            fp16
  u16* Kws = Qws + Q_ELEMS;              // [b][w][h][d]            fp16
  u16* Vws = Kws + Q_ELEMS;              // [b][w][g>>3][c][g&7]    fp16
  u16* W16 = Vws + V_ELEMS;              // [Wk16|Wq16|Wv16]        fp16
  u16* Tws = W16 + W16_ELEMS;            // [b][w][c][h]            fp16

  wconv_kernel<<<96, 256, 0, stream>>>(Wk, Wq, Wv, W16);
  qkv_kernel<<<2 * B_ * H_ * 2, 256, 0, stream>>>(flow, de_out, W16, bq, bk, bv,
                                                  Qws, Kws, Vws);
  if (ws_size >= (size_t)WS_NEED) {
    attn_kernel<1><<<B_ * W_, 512, 0, stream>>>(Qws, Kws, Vws, Tws, out);
    transpose_kernel<<<B_ * 512, 256, 0, stream>>>(Tws, out);
  } else {
    attn_kernel<0><<<B_ * W_, 512, 0, stream>>>(Qws, Kws, Vws, Tws, out);
  }
}